// Round 9
// baseline (94.587 us; speedup 1.0000x reference)
//
#include <hip/hip_runtime.h>
#include <math.h>

// IFS transforms: T = 4^6 = 4096 composed inverse affines, 8192 query points,
// 4 circle SDFs, global min over (t, k) per point.
// Round 7 (2nd resubmit after GPU acquisition timeouts): LDS-pressure fix.
// One broadcast ds_read_b128 serves 64 lanes x P points; at P=2 the kernel
// was LDS-issue-bound (49K LDS-cyc/CU = 20.5us). P=8 points/lane (TPB=128,
// 512 blocks) cuts LDS to 5.1us; VALU (~9.5us) becomes binding. Grouped
// squared-domain min (20 multiset groups/chunk) keeps sqrt hoisted.

#define NA 4
#define T_TOTAL 4096   // 4^DEPTH, DEPTH=6 (fixed by harness)
#define BATCH 8192
#define TPB 128
#define TCHUNK 64      // one hi (first 3 digits) per chunk
#define NCHUNK 64
#define PPL 8          // points per lane

__device__ __forceinline__ float fsqrt(float x) { return __builtin_amdgcn_sqrtf(x); }

// 64 last-3-digit combos (d3*16+d4*4+d5) grouped by digit multiset:
// slots 0-3: singles; slots 4-39: 12 pair-groups of 3; 40-63: 4 triple-groups of 6.
__constant__ unsigned char LO_COMBO[64] = {
    0, 21, 42, 63,
    1, 4, 16,   2, 8, 32,   3, 12, 48,
    20, 17, 5,  22, 25, 37, 23, 29, 53,
    40, 34, 10, 41, 38, 26, 43, 46, 58,
    60, 51, 15, 61, 55, 31, 62, 59, 47,
    6, 9, 18, 24, 33, 36,
    7, 13, 19, 28, 49, 52,
    11, 14, 35, 44, 50, 56,
    27, 30, 39, 45, 54, 57
};

// ---------------- shared device helpers ----------------

__device__ __forceinline__ void compute_inverses(const float* __restrict__ mats,
                                                 const float* __restrict__ scales,
                                                 float (*inv)[8], int tid) {
    // inv[n] = {i00, i01, i10, i11, tx, ty, scale, pad}
    if (tid < NA) {
        const int n = tid;
        float a = mats[n * 9 + 0], b = mats[n * 9 + 1], e = mats[n * 9 + 2];
        float c = mats[n * 9 + 3], d = mats[n * 9 + 4], f = mats[n * 9 + 5];
        float rd = 1.0f / (a * d - b * c);
        float i00 = d * rd, i01 = -b * rd, i10 = -c * rd, i11 = a * rd;
        inv[n][0] = i00; inv[n][1] = i01; inv[n][2] = i10; inv[n][3] = i11;
        inv[n][4] = -(i00 * e + i01 * f);
        inv[n][5] = -(i10 * e + i11 * f);
        inv[n][6] = scales[n];
        inv[n][7] = 0.0f;
    }
}

// Generate the chunk for hi (first-3-digits value 0..63) into xf, in
// multiset-grouped slot order. xf[i][k] = (wx, wy, ee, rsp).
__device__ __forceinline__ void gen_transforms(const float (*inv)[8], float4 (*xf)[4],
                                               int hi, int tid, int nthreads,
                                               const float* __restrict__ centers,
                                               const float* __restrict__ radii) {
    for (int i = tid; i < TCHUNK; i += nthreads) {
        int t = hi * 64 + (int)LO_COMBO[i];
        int dg = (t >> 10) & 3;  // most-significant base-4 digit
        float m00 = inv[dg][0], m01 = inv[dg][1], m10 = inv[dg][2], m11 = inv[dg][3];
        float tx = inv[dg][4], ty = inv[dg][5], sp = inv[dg][6];
        #pragma unroll
        for (int s = 8; s >= 0; s -= 2) {
            dg = (t >> s) & 3;
            float b00 = inv[dg][0], b01 = inv[dg][1], b10 = inv[dg][2], b11 = inv[dg][3];
            float bx = inv[dg][4], by = inv[dg][5];
            float n00 = fmaf(m00, b00, m01 * b10);
            float n01 = fmaf(m00, b01, m01 * b11);
            float n10 = fmaf(m10, b00, m11 * b10);
            float n11 = fmaf(m10, b01, m11 * b11);
            float nx  = fmaf(m00, bx, fmaf(m01, by, tx));
            float ny  = fmaf(m10, bx, fmaf(m11, by, ty));
            m00 = n00; m01 = n01; m10 = n10; m11 = n11; tx = nx; ty = ny;
            sp *= inv[dg][6];
        }
        // R = sp * M is orthogonal; e_k = (t - c_k)*sp.
        float R00 = m00 * sp, R01 = m01 * sp, R10 = m10 * sp, R11 = m11 * sp;
        #pragma unroll
        for (int k = 0; k < 4; ++k) {
            float ex = (tx - centers[2 * k + 0]) * sp;
            float ey = (ty - centers[2 * k + 1]) * sp;
            float wx = 2.0f * fmaf(R00, ex, R10 * ey);  // (2 R^T e).x
            float wy = 2.0f * fmaf(R01, ex, R11 * ey);  // (2 R^T e).y
            float ee = fmaf(ex, ex, ey * ey);
            xf[i][k] = make_float4(wx, wy, ee, radii[k] * sp);
        }
    }
}

// One multiset group of SZ transforms at [slot, slot+SZ), PPL points per lane:
// squared-domain min per (point, circle), single sqrt per (point, circle),
// then collapse circles into d[p].
template <int SZ>
__device__ __forceinline__ void group_eval8(const float4 (*xf)[4], int slot,
                                            const float* qx, const float* qy,
                                            const float* qq, float* d) {
    float sm[PPL][4];
    float rsp[4];
    #pragma unroll
    for (int k = 0; k < 4; ++k) {
        float4 W = xf[slot][k];  // LDS broadcast: all lanes same address
        rsp[k] = W.w;
        #pragma unroll
        for (int p = 0; p < PPL; ++p)
            sm[p][k] = fmaf(W.x, qx[p], fmaf(W.y, qy[p], W.z));
    }
    #pragma unroll
    for (int i = 1; i < SZ; ++i) {
        #pragma unroll
        for (int k = 0; k < 4; ++k) {
            float4 W = xf[slot + i][k];
            #pragma unroll
            for (int p = 0; p < PPL; ++p)
                sm[p][k] = fminf(sm[p][k], fmaf(W.x, qx[p], fmaf(W.y, qy[p], W.z)));
        }
    }
    #pragma unroll
    for (int p = 0; p < PPL; ++p) {
        #pragma unroll
        for (int k = 0; k < 4; ++k)
            d[p] = fminf(d[p], fsqrt(fmaxf(sm[p][k] + qq[p], 0.0f)) - rsp[k]);
    }
}

__device__ __forceinline__ void accum_grouped8(const float4 (*xf)[4],
                                               const float* qx, const float* qy,
                                               const float* qq, float* d) {
    // 4 singles (rolled: LDS addr may be runtime; q/d arrays statically indexed inside)
    #pragma unroll 1
    for (int a = 0; a < 4; ++a)
        group_eval8<1>(xf, a, qx, qy, qq, d);
    // 12 pair-groups of 3
    #pragma unroll 1
    for (int m = 0; m < 12; ++m)
        group_eval8<3>(xf, 4 + 3 * m, qx, qy, qq, d);
    // 4 triple-groups of 6
    #pragma unroll 1
    for (int g = 0; g < 4; ++g)
        group_eval8<6>(xf, 40 + 6 * g, qx, qy, qq, d);
}

// ---------------- kernels ----------------

__global__ __launch_bounds__(TPB) void ifs_partial8(const float* __restrict__ query,
                                                    const float* __restrict__ scales,
                                                    const float* __restrict__ mats,
                                                    const float* __restrict__ centers,
                                                    const float* __restrict__ radii,
                                                    float* __restrict__ partial) {
    __shared__ float inv[NA][8];
    __shared__ float4 xf[TCHUNK][4];
    const int tid = threadIdx.x;

    compute_inverses(mats, scales, inv, tid);
    __syncthreads();

    gen_transforms(inv, xf, blockIdx.y, tid, TPB, centers, radii);
    __syncthreads();

    // Block covers PPL*TPB = 1024 consecutive points; lane p-th point strided
    // by TPB for coalesced loads/stores.
    const int base = blockIdx.x * (PPL * TPB) + tid;
    const float2* q2 = (const float2*)query;

    float qx[PPL], qy[PPL], qq[PPL], d[PPL];
    #pragma unroll
    for (int p = 0; p < PPL; ++p) {
        float2 q = q2[base + p * TPB];
        qx[p] = q.x; qy[p] = q.y;
        qq[p] = fmaf(q.x, q.x, q.y * q.y);
        d[p] = INFINITY;
    }

    accum_grouped8(xf, qx, qy, qq, d);

    float* prow = partial + blockIdx.y * BATCH + base;
    #pragma unroll
    for (int p = 0; p < PPL; ++p) prow[p * TPB] = d[p];
}

__global__ __launch_bounds__(256) void ifs_reduce(const float* __restrict__ partial,
                                                  float* __restrict__ out) {
    const int b = blockIdx.x * 256 + threadIdx.x;
    float m = INFINITY;
    #pragma unroll
    for (int c = 0; c < NCHUNK; ++c) m = fminf(m, partial[c * BATCH + b]);
    out[b] = m;
}

// Fallback: no workspace needed (used only if ws_size is tiny). P=2 variant.
__global__ __launch_bounds__(256) void ifs_mono(const float* __restrict__ query,
                                                const float* __restrict__ scales,
                                                const float* __restrict__ mats,
                                                const float* __restrict__ centers,
                                                const float* __restrict__ radii,
                                                float* __restrict__ out) {
    __shared__ float inv[NA][8];
    __shared__ float4 xf[TCHUNK][4];
    const int tid = threadIdx.x;

    compute_inverses(mats, scales, inv, tid);
    __syncthreads();

    const int pb = blockIdx.x * 256 + tid;
    float4 qv = ((const float4*)query)[pb];
    float qx[2] = {qv.x, qv.z}, qy[2] = {qv.y, qv.w};
    float qq[2] = {fmaf(qv.x, qv.x, qv.y * qv.y), fmaf(qv.z, qv.z, qv.w * qv.w)};
    float d[2] = {INFINITY, INFINITY};

    for (int hi = 0; hi < NCHUNK; ++hi) {
        __syncthreads();
        gen_transforms(inv, xf, hi, tid, 256, centers, radii);
        __syncthreads();
        // reuse group structure at P=2 via small local arrays
        float sm[2][4], rsp[4];
        // singles
        #pragma unroll 1
        for (int a = 0; a < 4; ++a) {
            #pragma unroll
            for (int k = 0; k < 4; ++k) {
                float4 W = xf[a][k]; rsp[k] = W.w;
                #pragma unroll
                for (int p = 0; p < 2; ++p)
                    sm[p][k] = fmaf(W.x, qx[p], fmaf(W.y, qy[p], W.z));
            }
            #pragma unroll
            for (int p = 0; p < 2; ++p)
                #pragma unroll
                for (int k = 0; k < 4; ++k)
                    d[p] = fminf(d[p], fsqrt(fmaxf(sm[p][k] + qq[p], 0.0f)) - rsp[k]);
        }
        #pragma unroll 1
        for (int m = 0; m < 12; ++m) {
            int slot = 4 + 3 * m;
            #pragma unroll
            for (int k = 0; k < 4; ++k) {
                float4 W = xf[slot][k]; rsp[k] = W.w;
                #pragma unroll
                for (int p = 0; p < 2; ++p)
                    sm[p][k] = fmaf(W.x, qx[p], fmaf(W.y, qy[p], W.z));
            }
            #pragma unroll
            for (int i = 1; i < 3; ++i)
                #pragma unroll
                for (int k = 0; k < 4; ++k) {
                    float4 W = xf[slot + i][k];
                    #pragma unroll
                    for (int p = 0; p < 2; ++p)
                        sm[p][k] = fminf(sm[p][k], fmaf(W.x, qx[p], fmaf(W.y, qy[p], W.z)));
                }
            #pragma unroll
            for (int p = 0; p < 2; ++p)
                #pragma unroll
                for (int k = 0; k < 4; ++k)
                    d[p] = fminf(d[p], fsqrt(fmaxf(sm[p][k] + qq[p], 0.0f)) - rsp[k]);
        }
        #pragma unroll 1
        for (int g = 0; g < 4; ++g) {
            int slot = 40 + 6 * g;
            #pragma unroll
            for (int k = 0; k < 4; ++k) {
                float4 W = xf[slot][k]; rsp[k] = W.w;
                #pragma unroll
                for (int p = 0; p < 2; ++p)
                    sm[p][k] = fmaf(W.x, qx[p], fmaf(W.y, qy[p], W.z));
            }
            #pragma unroll
            for (int i = 1; i < 6; ++i)
                #pragma unroll
                for (int k = 0; k < 4; ++k) {
                    float4 W = xf[slot + i][k];
                    #pragma unroll
                    for (int p = 0; p < 2; ++p)
                        sm[p][k] = fminf(sm[p][k], fmaf(W.x, qx[p], fmaf(W.y, qy[p], W.z)));
                }
            #pragma unroll
            for (int p = 0; p < 2; ++p)
                #pragma unroll
                for (int k = 0; k < 4; ++k)
                    d[p] = fminf(d[p], fsqrt(fmaxf(sm[p][k] + qq[p], 0.0f)) - rsp[k]);
        }
    }
    ((float2*)out)[pb] = make_float2(d[0], d[1]);
}

// ---------------- launch ----------------

extern "C" void kernel_launch(void* const* d_in, const int* in_sizes, int n_in,
                              void* d_out, int out_size, void* d_ws, size_t ws_size,
                              hipStream_t stream) {
    const float* query   = (const float*)d_in[0];
    const float* scales  = (const float*)d_in[1];
    const float* mats    = (const float*)d_in[2];
    const float* centers = (const float*)d_in[3];
    const float* radii   = (const float*)d_in[4];
    // d_in[5] = depth (scalar) — fixed at 6, baked into T_TOTAL and digit shifts.
    float* out = (float*)d_out;

    const size_t needed = (size_t)NCHUNK * BATCH * sizeof(float);

    if (ws_size >= needed) {
        float* partial = (float*)d_ws;
        dim3 grid(BATCH / (TPB * PPL), NCHUNK);   // 8 x 64 = 512 blocks, TPB=128
        ifs_partial8<<<grid, TPB, 0, stream>>>(query, scales, mats, centers,
                                               radii, partial);
        ifs_reduce<<<BATCH / 256, 256, 0, stream>>>(partial, out);
    } else {
        ifs_mono<<<BATCH / (256 * 2), 256, 0, stream>>>(query, scales, mats, centers,
                                                        radii, out);
    }
}

// Round 11
// 80.626 us; speedup vs baseline: 1.1732x; 1.1732x over previous
//
#include <hip/hip_runtime.h>
#include <math.h>

// IFS transforms: T = 4^6 = 4096 composed inverse affines, 8192 query points,
// 4 circle SDFs, global min over (t, k) per point.
// Round 10 (resubmit after GPU acquisition timeout): P=8/TPB=128 regressed
// (1 wave/SIMD -> no latency hiding; group-boundary lgkmcnt and sqrt chains
// fully exposed). P=4/TPB=256 keeps the broadcast amortization (LDS model:
// 8 waves/CU x 256 b128 x 12cyc = 10.2us) AND 2 waves/SIMD of hiding (VALU
// ~8.8us). Balanced ~11-13us partial.

#define NA 4
#define T_TOTAL 4096   // 4^DEPTH, DEPTH=6 (fixed by harness)
#define BATCH 8192
#define TPB 256
#define TCHUNK 64      // one hi (first 3 digits) per chunk
#define NCHUNK 64
#define PPL 4          // points per lane

__device__ __forceinline__ float fsqrt(float x) { return __builtin_amdgcn_sqrtf(x); }

// 64 last-3-digit combos (d3*16+d4*4+d5) grouped by digit multiset:
// slots 0-3: singles; slots 4-39: 12 pair-groups of 3; 40-63: 4 triple-groups of 6.
__constant__ unsigned char LO_COMBO[64] = {
    0, 21, 42, 63,
    1, 4, 16,   2, 8, 32,   3, 12, 48,
    20, 17, 5,  22, 25, 37, 23, 29, 53,
    40, 34, 10, 41, 38, 26, 43, 46, 58,
    60, 51, 15, 61, 55, 31, 62, 59, 47,
    6, 9, 18, 24, 33, 36,
    7, 13, 19, 28, 49, 52,
    11, 14, 35, 44, 50, 56,
    27, 30, 39, 45, 54, 57
};

// ---------------- shared device helpers ----------------

__device__ __forceinline__ void compute_inverses(const float* __restrict__ mats,
                                                 const float* __restrict__ scales,
                                                 float (*inv)[8], int tid) {
    // inv[n] = {i00, i01, i10, i11, tx, ty, scale, pad}
    if (tid < NA) {
        const int n = tid;
        float a = mats[n * 9 + 0], b = mats[n * 9 + 1], e = mats[n * 9 + 2];
        float c = mats[n * 9 + 3], d = mats[n * 9 + 4], f = mats[n * 9 + 5];
        float rd = 1.0f / (a * d - b * c);
        float i00 = d * rd, i01 = -b * rd, i10 = -c * rd, i11 = a * rd;
        inv[n][0] = i00; inv[n][1] = i01; inv[n][2] = i10; inv[n][3] = i11;
        inv[n][4] = -(i00 * e + i01 * f);
        inv[n][5] = -(i10 * e + i11 * f);
        inv[n][6] = scales[n];
        inv[n][7] = 0.0f;
    }
}

// Generate the chunk for hi (first-3-digits value 0..63) into xf, in
// multiset-grouped slot order. xf[i][k] = (wx, wy, ee, rsp).
__device__ __forceinline__ void gen_transforms(const float (*inv)[8], float4 (*xf)[4],
                                               int hi, int tid, int nthreads,
                                               const float* __restrict__ centers,
                                               const float* __restrict__ radii) {
    for (int i = tid; i < TCHUNK; i += nthreads) {
        int t = hi * 64 + (int)LO_COMBO[i];
        int dg = (t >> 10) & 3;  // most-significant base-4 digit
        float m00 = inv[dg][0], m01 = inv[dg][1], m10 = inv[dg][2], m11 = inv[dg][3];
        float tx = inv[dg][4], ty = inv[dg][5], sp = inv[dg][6];
        #pragma unroll
        for (int s = 8; s >= 0; s -= 2) {
            dg = (t >> s) & 3;
            float b00 = inv[dg][0], b01 = inv[dg][1], b10 = inv[dg][2], b11 = inv[dg][3];
            float bx = inv[dg][4], by = inv[dg][5];
            float n00 = fmaf(m00, b00, m01 * b10);
            float n01 = fmaf(m00, b01, m01 * b11);
            float n10 = fmaf(m10, b00, m11 * b10);
            float n11 = fmaf(m10, b01, m11 * b11);
            float nx  = fmaf(m00, bx, fmaf(m01, by, tx));
            float ny  = fmaf(m10, bx, fmaf(m11, by, ty));
            m00 = n00; m01 = n01; m10 = n10; m11 = n11; tx = nx; ty = ny;
            sp *= inv[dg][6];
        }
        // R = sp * M is orthogonal; e_k = (t - c_k)*sp.
        float R00 = m00 * sp, R01 = m01 * sp, R10 = m10 * sp, R11 = m11 * sp;
        #pragma unroll
        for (int k = 0; k < 4; ++k) {
            float ex = (tx - centers[2 * k + 0]) * sp;
            float ey = (ty - centers[2 * k + 1]) * sp;
            float wx = 2.0f * fmaf(R00, ex, R10 * ey);  // (2 R^T e).x
            float wy = 2.0f * fmaf(R01, ex, R11 * ey);  // (2 R^T e).y
            float ee = fmaf(ex, ex, ey * ey);
            xf[i][k] = make_float4(wx, wy, ee, radii[k] * sp);
        }
    }
}

// One multiset group of SZ transforms at [slot, slot+SZ), PPL points per lane:
// squared-domain min per (point, circle), single sqrt per (point, circle),
// then collapse circles into d[p].
template <int SZ>
__device__ __forceinline__ void group_evalP(const float4 (*xf)[4], int slot,
                                            const float* qx, const float* qy,
                                            const float* qq, float* d) {
    float sm[PPL][4];
    float rsp[4];
    #pragma unroll
    for (int k = 0; k < 4; ++k) {
        float4 W = xf[slot][k];  // LDS broadcast: all lanes same address
        rsp[k] = W.w;
        #pragma unroll
        for (int p = 0; p < PPL; ++p)
            sm[p][k] = fmaf(W.x, qx[p], fmaf(W.y, qy[p], W.z));
    }
    #pragma unroll
    for (int i = 1; i < SZ; ++i) {
        #pragma unroll
        for (int k = 0; k < 4; ++k) {
            float4 W = xf[slot + i][k];
            #pragma unroll
            for (int p = 0; p < PPL; ++p)
                sm[p][k] = fminf(sm[p][k], fmaf(W.x, qx[p], fmaf(W.y, qy[p], W.z)));
        }
    }
    #pragma unroll
    for (int p = 0; p < PPL; ++p) {
        #pragma unroll
        for (int k = 0; k < 4; ++k)
            d[p] = fminf(d[p], fsqrt(fmaxf(sm[p][k] + qq[p], 0.0f)) - rsp[k]);
    }
}

__device__ __forceinline__ void accum_groupedP(const float4 (*xf)[4],
                                               const float* qx, const float* qy,
                                               const float* qq, float* d) {
    // rolled group loops: code stays I-cache-resident; 2 waves/SIMD hide
    // the group-boundary lgkmcnt waits.
    #pragma unroll 1
    for (int a = 0; a < 4; ++a)
        group_evalP<1>(xf, a, qx, qy, qq, d);
    #pragma unroll 1
    for (int m = 0; m < 12; ++m)
        group_evalP<3>(xf, 4 + 3 * m, qx, qy, qq, d);
    #pragma unroll 1
    for (int g = 0; g < 4; ++g)
        group_evalP<6>(xf, 40 + 6 * g, qx, qy, qq, d);
}

// ---------------- kernels ----------------

__global__ __launch_bounds__(TPB) void ifs_partial4(const float* __restrict__ query,
                                                    const float* __restrict__ scales,
                                                    const float* __restrict__ mats,
                                                    const float* __restrict__ centers,
                                                    const float* __restrict__ radii,
                                                    float* __restrict__ partial) {
    __shared__ float inv[NA][8];
    __shared__ float4 xf[TCHUNK][4];
    const int tid = threadIdx.x;

    compute_inverses(mats, scales, inv, tid);
    __syncthreads();

    gen_transforms(inv, xf, blockIdx.y, tid, TPB, centers, radii);
    __syncthreads();

    // Block covers PPL*TPB = 1024 consecutive points; lane's p-th point
    // strided by TPB for coalesced loads/stores.
    const int base = blockIdx.x * (PPL * TPB) + tid;
    const float2* q2 = (const float2*)query;

    float qx[PPL], qy[PPL], qq[PPL], d[PPL];
    #pragma unroll
    for (int p = 0; p < PPL; ++p) {
        float2 q = q2[base + p * TPB];
        qx[p] = q.x; qy[p] = q.y;
        qq[p] = fmaf(q.x, q.x, q.y * q.y);
        d[p] = INFINITY;
    }

    accum_groupedP(xf, qx, qy, qq, d);

    float* prow = partial + blockIdx.y * BATCH + base;
    #pragma unroll
    for (int p = 0; p < PPL; ++p) prow[p * TPB] = d[p];
}

__global__ __launch_bounds__(256) void ifs_reduce(const float* __restrict__ partial,
                                                  float* __restrict__ out) {
    const int b = blockIdx.x * 256 + threadIdx.x;
    float m = INFINITY;
    #pragma unroll
    for (int c = 0; c < NCHUNK; ++c) m = fminf(m, partial[c * BATCH + b]);
    out[b] = m;
}

// Fallback: no workspace needed (used only if ws_size is tiny). P=2 variant.
__global__ __launch_bounds__(256) void ifs_mono(const float* __restrict__ query,
                                                const float* __restrict__ scales,
                                                const float* __restrict__ mats,
                                                const float* __restrict__ centers,
                                                const float* __restrict__ radii,
                                                float* __restrict__ out) {
    __shared__ float inv[NA][8];
    __shared__ float4 xf[TCHUNK][4];
    const int tid = threadIdx.x;

    compute_inverses(mats, scales, inv, tid);
    __syncthreads();

    const int pb = blockIdx.x * 256 + tid;
    float4 qv = ((const float4*)query)[pb];
    float qx[2] = {qv.x, qv.z}, qy[2] = {qv.y, qv.w};
    float qq[2] = {fmaf(qv.x, qv.x, qv.y * qv.y), fmaf(qv.z, qv.z, qv.w * qv.w)};
    float d[2] = {INFINITY, INFINITY};

    for (int hi = 0; hi < NCHUNK; ++hi) {
        __syncthreads();
        gen_transforms(inv, xf, hi, tid, 256, centers, radii);
        __syncthreads();
        float sm[2][4], rsp[4];
        #pragma unroll 1
        for (int a = 0; a < 4; ++a) {
            #pragma unroll
            for (int k = 0; k < 4; ++k) {
                float4 W = xf[a][k]; rsp[k] = W.w;
                #pragma unroll
                for (int p = 0; p < 2; ++p)
                    sm[p][k] = fmaf(W.x, qx[p], fmaf(W.y, qy[p], W.z));
            }
            #pragma unroll
            for (int p = 0; p < 2; ++p)
                #pragma unroll
                for (int k = 0; k < 4; ++k)
                    d[p] = fminf(d[p], fsqrt(fmaxf(sm[p][k] + qq[p], 0.0f)) - rsp[k]);
        }
        #pragma unroll 1
        for (int m = 0; m < 12; ++m) {
            int slot = 4 + 3 * m;
            #pragma unroll
            for (int k = 0; k < 4; ++k) {
                float4 W = xf[slot][k]; rsp[k] = W.w;
                #pragma unroll
                for (int p = 0; p < 2; ++p)
                    sm[p][k] = fmaf(W.x, qx[p], fmaf(W.y, qy[p], W.z));
            }
            #pragma unroll
            for (int i = 1; i < 3; ++i)
                #pragma unroll
                for (int k = 0; k < 4; ++k) {
                    float4 W = xf[slot + i][k];
                    #pragma unroll
                    for (int p = 0; p < 2; ++p)
                        sm[p][k] = fminf(sm[p][k], fmaf(W.x, qx[p], fmaf(W.y, qy[p], W.z)));
                }
            #pragma unroll
            for (int p = 0; p < 2; ++p)
                #pragma unroll
                for (int k = 0; k < 4; ++k)
                    d[p] = fminf(d[p], fsqrt(fmaxf(sm[p][k] + qq[p], 0.0f)) - rsp[k]);
        }
        #pragma unroll 1
        for (int g = 0; g < 4; ++g) {
            int slot = 40 + 6 * g;
            #pragma unroll
            for (int k = 0; k < 4; ++k) {
                float4 W = xf[slot][k]; rsp[k] = W.w;
                #pragma unroll
                for (int p = 0; p < 2; ++p)
                    sm[p][k] = fmaf(W.x, qx[p], fmaf(W.y, qy[p], W.z));
            }
            #pragma unroll
            for (int i = 1; i < 6; ++i)
                #pragma unroll
                for (int k = 0; k < 4; ++k) {
                    float4 W = xf[slot + i][k];
                    #pragma unroll
                    for (int p = 0; p < 2; ++p)
                        sm[p][k] = fminf(sm[p][k], fmaf(W.x, qx[p], fmaf(W.y, qy[p], W.z)));
                }
            #pragma unroll
            for (int p = 0; p < 2; ++p)
                #pragma unroll
                for (int k = 0; k < 4; ++k)
                    d[p] = fminf(d[p], fsqrt(fmaxf(sm[p][k] + qq[p], 0.0f)) - rsp[k]);
        }
    }
    ((float2*)out)[pb] = make_float2(d[0], d[1]);
}

// ---------------- launch ----------------

extern "C" void kernel_launch(void* const* d_in, const int* in_sizes, int n_in,
                              void* d_out, int out_size, void* d_ws, size_t ws_size,
                              hipStream_t stream) {
    const float* query   = (const float*)d_in[0];
    const float* scales  = (const float*)d_in[1];
    const float* mats    = (const float*)d_in[2];
    const float* centers = (const float*)d_in[3];
    const float* radii   = (const float*)d_in[4];
    // d_in[5] = depth (scalar) — fixed at 6, baked into T_TOTAL and digit shifts.
    float* out = (float*)d_out;

    const size_t needed = (size_t)NCHUNK * BATCH * sizeof(float);

    if (ws_size >= needed) {
        float* partial = (float*)d_ws;
        dim3 grid(BATCH / (TPB * PPL), NCHUNK);   // 8 x 64 = 512 blocks, TPB=256
        ifs_partial4<<<grid, TPB, 0, stream>>>(query, scales, mats, centers,
                                               radii, partial);
        ifs_reduce<<<BATCH / 256, 256, 0, stream>>>(partial, out);
    } else {
        ifs_mono<<<BATCH / (256 * 2), 256, 0, stream>>>(query, scales, mats, centers,
                                                        radii, out);
    }
}